// Round 3
// baseline (492.885 us; speedup 1.0000x reference)
//
#include <hip/hip_runtime.h>

#define B_TOTAL   8192
#define CR_LEN    168
#define PR_LEN    24
#define HID       40
#define ROWS      6           // rows per block (6*40 = 240 active threads)
#define NTHREADS  256
#define OUT_STRIDE (B_TOTAL * PR_LEN)   // 196608

__device__ __forceinline__ float fast_rcp(float x) { return __builtin_amdgcn_rcpf(x); }

__device__ __forceinline__ float sigmoid_f(float x) {
    return fast_rcp(1.0f + __expf(-x));
}

__device__ __forceinline__ float tanh_f(float x) {
    float ax = fabsf(x);
    float e  = __expf(-2.0f * ax);
    float r  = (1.0f - e) * fast_rcp(1.0f + e);
    return copysignf(r, x);
}

__device__ __forceinline__ unsigned rotl32(unsigned x, int d) {
    return (x << d) | (x >> (32 - d));
}

// JAX threefry2x32 (20 rounds), general key — HW-KAT-verified in round 2
__device__ __forceinline__ void threefry2x32(unsigned k0, unsigned k1,
                                             unsigned c0, unsigned c1,
                                             unsigned& o0, unsigned& o1) {
    const unsigned k2 = 0x1BD11BDAu ^ k0 ^ k1;
    unsigned x0 = c0 + k0, x1 = c1 + k1;
#define TF_R(rr) { x0 += x1; x1 = rotl32(x1, (rr)); x1 ^= x0; }
    TF_R(13) TF_R(15) TF_R(26) TF_R(6)  x0 += k1; x1 += k2 + 1u;
    TF_R(17) TF_R(29) TF_R(16) TF_R(24) x0 += k2; x1 += k0 + 2u;
    TF_R(13) TF_R(15) TF_R(26) TF_R(6)  x0 += k0; x1 += k1 + 3u;
    TF_R(17) TF_R(29) TF_R(16) TF_R(24) x0 += k1; x1 += k2 + 4u;
    TF_R(13) TF_R(15) TF_R(26) TF_R(6)  x0 += k2; x1 += k0 + 5u;
#undef TF_R
    o0 = x0; o1 = x1;
}

// Giles single-precision erfinv (XLA ErfInv32 poly)
__device__ __forceinline__ float erfinv_f(float x) {
    float w = -__logf(fmaf(-x, x, 1.0f));
    float p;
    if (w < 5.0f) {
        w -= 2.5f;
        p = 2.81022636e-08f;
        p = fmaf(p, w, 3.43273939e-07f);
        p = fmaf(p, w, -3.5233877e-06f);
        p = fmaf(p, w, -4.39150654e-06f);
        p = fmaf(p, w, 0.00021858087f);
        p = fmaf(p, w, -0.00125372503f);
        p = fmaf(p, w, -0.00417768164f);
        p = fmaf(p, w, 0.246640727f);
        p = fmaf(p, w, 1.50140941f);
    } else {
        w = sqrtf(w) - 3.0f;
        p = -0.000200214257f;
        p = fmaf(p, w, 0.000100950558f);
        p = fmaf(p, w, 0.00134934322f);
        p = fmaf(p, w, -0.00367342844f);
        p = fmaf(p, w, 0.00573950773f);
        p = fmaf(p, w, -0.0076224613f);
        p = fmaf(p, w, 0.00943887047f);
        p = fmaf(p, w, 1.00167406f);
        p = fmaf(p, w, 2.83297682f);
    }
    return p * x;
}

// KAT tripwire (Random123 vectors) — poisons output if threefry core breaks
__device__ __forceinline__ float kat_poison() {
    float poison = 0.0f;
    unsigned o0, o1;
    threefry2x32(0u, 0u, 0u, 0u, o0, o1);
    bool ok1 = (o0 == 0x6b200159u) && (o1 == 0x99ba4efeu);
    threefry2x32(0xFFFFFFFFu, 0xFFFFFFFFu, 0xFFFFFFFFu, 0xFFFFFFFFu, o0, o1);
    bool ok2 = (o0 == 0x1cb996fcu) && (o1 == 0xbb002be7u);
    if (!(ok1 && ok2)) poison += 4096.0f;
    threefry2x32(0x13198a2eu, 0x03707344u, 0x243f6a88u, 0x85a308d3u, o0, o1);
    bool ok3 = (o0 == 0xc4923a9cu) && (o1 == 0x483df7a0u);
    if (!ok3) poison += 8192.0f;
    return poison;
}

__launch_bounds__(NTHREADS, 2)
__global__ void deepar_kernel(const float* __restrict__ z1,
                              const float* __restrict__ xc,
                              const float* __restrict__ W_emb,
                              const float* __restrict__ b_emb,
                              const float* __restrict__ W_ih,
                              const float* __restrict__ b_ih,
                              const float* __restrict__ W_hh,
                              const float* __restrict__ b_hh,
                              const float* __restrict__ W_mu,
                              const float* __restrict__ b_mu,
                              const float* __restrict__ W_sig,
                              const float* __restrict__ b_sig,
                              float* __restrict__ out) {
    __shared__ __align__(16) float z1_s[ROWS][CR_LEN];
    __shared__ __align__(16) float xc_s[ROWS][(CR_LEN + PR_LEN) * 3];
    __shared__ __align__(16) float h_s[ROWS][HID];
    __shared__ float eps_s[ROWS][PR_LEN];
    __shared__ float y_s[ROWS];
    __shared__ __align__(16) float wmu_s[HID];
    __shared__ __align__(16) float wsg_s[HID];
    __shared__ float bmu_s, bsg_s;

    const int tid = threadIdx.x;
    const int r   = tid / HID;
    const int j   = tid % HID;
    const int b0  = blockIdx.x * ROWS;
    const int b   = b0 + r;
    const bool active = (r < ROWS) && (b < B_TOTAL);

    {
        int nrow = B_TOTAL - b0;
        if (nrow > ROWS) nrow = ROWS;
        if (nrow < 0) nrow = 0;
        const float4* s1 = (const float4*)(z1 + (size_t)b0 * CR_LEN);
        float4* d1 = (float4*)&z1_s[0][0];
        const int n1 = nrow * (CR_LEN / 4);
        for (int idx = tid; idx < n1; idx += NTHREADS) d1[idx] = s1[idx];
        const float4* s2 = (const float4*)(xc + (size_t)b0 * (CR_LEN + PR_LEN) * 3);
        float4* d2 = (float4*)&xc_s[0][0];
        const int n2 = nrow * ((CR_LEN + PR_LEN) * 3 / 4);
        for (int idx = tid; idx < n2; idx += NTHREADS) d2[idx] = s2[idx];
    }
    if (tid < HID)                 wmu_s[tid] = W_mu[tid];
    else if (tid < 2 * HID)        wsg_s[tid - HID] = W_sig[tid - HID];
    else if (tid == 2 * HID)       bmu_s = b_mu[0];
    else if (tid == 2 * HID + 1)   bsg_s = b_sig[0];

    float4 w0[10], w1[10], w2[10], w3[10];
    {
        const float4* p0 = (const float4*)(W_hh + (0 * HID + j) * HID);
        const float4* p1 = (const float4*)(W_hh + (1 * HID + j) * HID);
        const float4* p2 = (const float4*)(W_hh + (2 * HID + j) * HID);
        const float4* p3 = (const float4*)(W_hh + (3 * HID + j) * HID);
#pragma unroll
        for (int q = 0; q < 10; q++) { w0[q] = p0[q]; w1[q] = p1[q]; w2[q] = p2[q]; w3[q] = p3[q]; }
    }

    float fA[4], fC[4], fx0[4], fx1[4], fx2[4];
#pragma unroll
    for (int g = 0; g < 4; g++) {
        const int row = g * HID + j;
        const float* wr = W_ih + row * 23;
        float a = 0.0f, cc = b_ih[row] + b_hh[row];
#pragma unroll
        for (int e = 0; e < 20; e++) {
            float wv = wr[e];
            a  = fmaf(wv, W_emb[e], a);
            cc = fmaf(wv, b_emb[e], cc);
        }
        fA[g] = a; fC[g] = cc;
        fx0[g] = wr[20]; fx1[g] = wr[21]; fx2[g] = wr[22];
    }

    __syncthreads();

    float v = 0.0f, inv_v = 0.0f;
    if (active) {
        float s = 0.0f;
#pragma unroll
        for (int q = 0; q < CR_LEN / 4; q++) {
            float4 zz = *(const float4*)&z1_s[r][4 * q];
            s += zz.x + zz.y + zz.z + zz.w;
        }
        v = s * (1.0f / (float)CR_LEN) + 1.0f;
        inv_v = 1.0f / v;
    }

    // ---- eps: JAX threefry PARTITIONABLE path (jax>=0.5 default) ----
    // flat index i -> counter (hi,lo) = (0, i); 32-bit bits = out0 ^ out1
    if (active && j < PR_LEN) {
        unsigned i = (unsigned)j * B_TOTAL + (unsigned)b;
        unsigned o0, o1;
        threefry2x32(0u, 42u, 0u, i, o0, o1);
        unsigned bits = o0 ^ o1;
        float f = __uint_as_float((bits >> 9) | 0x3F800000u) - 1.0f;  // [0,1)
        const float lo = -0.99999994f;                 // nextafter(-1,0)
        float u = fmaxf(lo, fmaf(f, 2.0f, lo));        // scale (hi-lo) == 2.0f
        eps_s[r][j] = 1.41421356237f * erfinv_f(u);
    }

    if (active) h_s[r][j] = 0.0f;
    float c_st = 0.0f, h_st = 0.0f;
    __syncthreads();

    auto lstm_step = [&](float z1n, float xa, float xb, float xv) {
        float a0 = fmaf(fA[0], z1n, fC[0]);
        float a1 = fmaf(fA[1], z1n, fC[1]);
        float a2 = fmaf(fA[2], z1n, fC[2]);
        float a3 = fmaf(fA[3], z1n, fC[3]);
        a0 = fmaf(fx0[0], xa, a0); a1 = fmaf(fx0[1], xa, a1);
        a2 = fmaf(fx0[2], xa, a2); a3 = fmaf(fx0[3], xa, a3);
        a0 = fmaf(fx1[0], xb, a0); a1 = fmaf(fx1[1], xb, a1);
        a2 = fmaf(fx1[2], xb, a2); a3 = fmaf(fx1[3], xb, a3);
        a0 = fmaf(fx2[0], xv, a0); a1 = fmaf(fx2[1], xv, a1);
        a2 = fmaf(fx2[2], xv, a2); a3 = fmaf(fx2[3], xv, a3);
#pragma unroll
        for (int q = 0; q < 10; q++) {
            float4 h4 = *(const float4*)&h_s[r][4 * q];
            a0 = fmaf(w0[q].x, h4.x, a0); a0 = fmaf(w0[q].y, h4.y, a0);
            a0 = fmaf(w0[q].z, h4.z, a0); a0 = fmaf(w0[q].w, h4.w, a0);
            a1 = fmaf(w1[q].x, h4.x, a1); a1 = fmaf(w1[q].y, h4.y, a1);
            a1 = fmaf(w1[q].z, h4.z, a1); a1 = fmaf(w1[q].w, h4.w, a1);
            a2 = fmaf(w2[q].x, h4.x, a2); a2 = fmaf(w2[q].y, h4.y, a2);
            a2 = fmaf(w2[q].z, h4.z, a2); a2 = fmaf(w2[q].w, h4.w, a2);
            a3 = fmaf(w3[q].x, h4.x, a3); a3 = fmaf(w3[q].y, h4.y, a3);
            a3 = fmaf(w3[q].z, h4.z, a3); a3 = fmaf(w3[q].w, h4.w, a3);
        }
        float gi = sigmoid_f(a0);
        float gf = sigmoid_f(a1);
        float gg = tanh_f(a2);
        float go = sigmoid_f(a3);
        c_st = fmaf(gf, c_st, gi * gg);
        h_st = go * tanh_f(c_st);
    };

    for (int t = 0; t < CR_LEN - 1; t++) {
        if (active) {
            float z1n = z1_s[r][t] * inv_v;
            float xa = xc_s[r][3 * (t + 1) + 0];
            float xb = xc_s[r][3 * (t + 1) + 1];
            float xv = xc_s[r][3 * (t + 1) + 2];
            lstm_step(z1n, xa, xb, xv);
        }
        __syncthreads();
        if (active) h_s[r][j] = h_st;
        __syncthreads();
    }

    if (active && j == 0) y_s[r] = z1_s[r][CR_LEN - 1];
    __syncthreads();

    for (int t = 0; t < PR_LEN; t++) {
        if (active) {
            float z1n = y_s[r] * inv_v;
            float xa = xc_s[r][3 * (CR_LEN + t) + 0];
            float xb = xc_s[r][3 * (CR_LEN + t) + 1];
            float xv = xc_s[r][3 * (CR_LEN + t) + 2];
            lstm_step(z1n, xa, xb, xv);
        }
        __syncthreads();
        if (active) h_s[r][j] = h_st;
        __syncthreads();
        if (active && j == 0) {
            float mu = bmu_s, sp = bsg_s;
#pragma unroll
            for (int q = 0; q < 10; q++) {
                float4 h4 = *(const float4*)&h_s[r][4 * q];
                float4 wm = *(const float4*)&wmu_s[4 * q];
                float4 ws = *(const float4*)&wsg_s[4 * q];
                mu = fmaf(wm.x, h4.x, mu); mu = fmaf(wm.y, h4.y, mu);
                mu = fmaf(wm.z, h4.z, mu); mu = fmaf(wm.w, h4.w, mu);
                sp = fmaf(ws.x, h4.x, sp); sp = fmaf(ws.y, h4.y, sp);
                sp = fmaf(ws.z, h4.z, sp); sp = fmaf(ws.w, h4.w, sp);
            }
            float sigma = fmaxf(sp, 0.0f) + log1pf(__expf(-fabsf(sp)));
            float y = fmaf(sigma, eps_s[r][t], mu);
            y_s[r] = y;
            const int ob = b * PR_LEN + t;
            float poison = (b == 0 && t == 0) ? kat_poison() : 0.0f;
            out[ob]                  = y * v + poison;
            out[OUT_STRIDE + ob]     = mu * v;
            out[2 * OUT_STRIDE + ob] = sigma * v;
        }
        __syncthreads();
    }
}

extern "C" void kernel_launch(void* const* d_in, const int* in_sizes, int n_in,
                              void* d_out, int out_size, void* d_ws, size_t ws_size,
                              hipStream_t stream) {
    const float* z1    = (const float*)d_in[0];
    const float* xc    = (const float*)d_in[1];
    const float* W_emb = (const float*)d_in[2];
    const float* b_emb = (const float*)d_in[3];
    const float* W_ih  = (const float*)d_in[4];
    const float* b_ih  = (const float*)d_in[5];
    const float* W_hh  = (const float*)d_in[6];
    const float* b_hh  = (const float*)d_in[7];
    const float* W_mu  = (const float*)d_in[8];
    const float* b_mu  = (const float*)d_in[9];
    const float* W_sig = (const float*)d_in[10];
    const float* b_sig = (const float*)d_in[11];
    float* out = (float*)d_out;

    dim3 grid((B_TOTAL + ROWS - 1) / ROWS);
    dim3 block(NTHREADS);
    deepar_kernel<<<grid, block, 0, stream>>>(z1, xc, W_emb, b_emb, W_ih, b_ih,
                                              W_hh, b_hh, W_mu, b_mu, W_sig, b_sig,
                                              out);
}

// Round 4
// 486.840 us; speedup vs baseline: 1.0124x; 1.0124x over previous
//
#include <hip/hip_runtime.h>

#define B_TOTAL   8192
#define CR_LEN    168
#define PR_LEN    24
#define HID       40
#define ROWS      6           // rows per block (6*40 = 240 active threads)
#define NTHREADS  256
#define OUT_STRIDE (B_TOTAL * PR_LEN)   // 196608

__device__ __forceinline__ float fast_rcp(float x) { return __builtin_amdgcn_rcpf(x); }

__device__ __forceinline__ float sigmoid_f(float x) {
    return fast_rcp(1.0f + __expf(-x));
}

__device__ __forceinline__ float tanh_f(float x) {
    float ax = fabsf(x);
    float e  = __expf(-2.0f * ax);
    float r  = (1.0f - e) * fast_rcp(1.0f + e);
    return copysignf(r, x);
}

__device__ __forceinline__ unsigned rotl32(unsigned x, int d) {
    return (x << d) | (x >> (32 - d));
}

// JAX threefry2x32 (20 rounds) — HW-KAT-verified (round 2)
__device__ __forceinline__ void threefry2x32(unsigned k0, unsigned k1,
                                             unsigned c0, unsigned c1,
                                             unsigned& o0, unsigned& o1) {
    const unsigned k2 = 0x1BD11BDAu ^ k0 ^ k1;
    unsigned x0 = c0 + k0, x1 = c1 + k1;
#define TF_R(rr) { x0 += x1; x1 = rotl32(x1, (rr)); x1 ^= x0; }
    TF_R(13) TF_R(15) TF_R(26) TF_R(6)  x0 += k1; x1 += k2 + 1u;
    TF_R(17) TF_R(29) TF_R(16) TF_R(24) x0 += k2; x1 += k0 + 2u;
    TF_R(13) TF_R(15) TF_R(26) TF_R(6)  x0 += k0; x1 += k1 + 3u;
    TF_R(17) TF_R(29) TF_R(16) TF_R(24) x0 += k1; x1 += k2 + 4u;
    TF_R(13) TF_R(15) TF_R(26) TF_R(6)  x0 += k2; x1 += k0 + 5u;
#undef TF_R
    o0 = x0; o1 = x1;
}

// Giles single-precision erfinv (XLA ErfInv32 poly)
__device__ __forceinline__ float erfinv_f(float x) {
    float w = -__logf(fmaf(-x, x, 1.0f));
    float p;
    if (w < 5.0f) {
        w -= 2.5f;
        p = 2.81022636e-08f;
        p = fmaf(p, w, 3.43273939e-07f);
        p = fmaf(p, w, -3.5233877e-06f);
        p = fmaf(p, w, -4.39150654e-06f);
        p = fmaf(p, w, 0.00021858087f);
        p = fmaf(p, w, -0.00125372503f);
        p = fmaf(p, w, -0.00417768164f);
        p = fmaf(p, w, 0.246640727f);
        p = fmaf(p, w, 1.50140941f);
    } else {
        w = sqrtf(w) - 3.0f;
        p = -0.000200214257f;
        p = fmaf(p, w, 0.000100950558f);
        p = fmaf(p, w, 0.00134934322f);
        p = fmaf(p, w, -0.00367342844f);
        p = fmaf(p, w, 0.00573950773f);
        p = fmaf(p, w, -0.0076224613f);
        p = fmaf(p, w, 0.00943887047f);
        p = fmaf(p, w, 1.00167406f);
        p = fmaf(p, w, 2.83297682f);
    }
    return p * x;
}

// KAT tripwire (Random123 vectors)
__device__ __forceinline__ float kat_poison() {
    float poison = 0.0f;
    unsigned o0, o1;
    threefry2x32(0u, 0u, 0u, 0u, o0, o1);
    bool ok1 = (o0 == 0x6b200159u) && (o1 == 0x99ba4efeu);
    threefry2x32(0xFFFFFFFFu, 0xFFFFFFFFu, 0xFFFFFFFFu, 0xFFFFFFFFu, o0, o1);
    bool ok2 = (o0 == 0x1cb996fcu) && (o1 == 0xbb002be7u);
    if (!(ok1 && ok2)) poison += 4096.0f;
    threefry2x32(0x13198a2eu, 0x03707344u, 0x243f6a88u, 0x85a308d3u, o0, o1);
    bool ok3 = (o0 == 0xc4923a9cu) && (o1 == 0x483df7a0u);
    if (!ok3) poison += 8192.0f;
    return poison;
}

// launch_bounds(256,1): allow up to 512 VGPRs so the 160-float W_hh stash
// stays in registers (VGPR=120 in R3 proved it was spilling to scratch).
__launch_bounds__(NTHREADS, 1)
__global__ void deepar_kernel(const float* __restrict__ z1,
                              const float* __restrict__ xc,
                              const float* __restrict__ W_emb,
                              const float* __restrict__ b_emb,
                              const float* __restrict__ W_ih,
                              const float* __restrict__ b_ih,
                              const float* __restrict__ W_hh,
                              const float* __restrict__ b_hh,
                              const float* __restrict__ W_mu,
                              const float* __restrict__ b_mu,
                              const float* __restrict__ W_sig,
                              const float* __restrict__ b_sig,
                              float* __restrict__ out) {
    __shared__ __align__(16) float z1_s[ROWS][CR_LEN];
    __shared__ __align__(16) float xc_s[ROWS][(CR_LEN + PR_LEN) * 3];
    __shared__ __align__(16) float h_s[2][ROWS][HID];   // double buffer -> 1 barrier/step
    __shared__ float eps_s[ROWS][PR_LEN];
    __shared__ float y_s[ROWS];
    __shared__ __align__(16) float wmu_s[HID];
    __shared__ __align__(16) float wsg_s[HID];
    __shared__ float bmu_s, bsg_s;

    const int tid = threadIdx.x;
    const int r   = tid / HID;
    const int j   = tid % HID;
    const int b0  = blockIdx.x * ROWS;
    const int b   = b0 + r;
    const bool active = (r < ROWS) && (b < B_TOTAL);

    {
        int nrow = B_TOTAL - b0;
        if (nrow > ROWS) nrow = ROWS;
        if (nrow < 0) nrow = 0;
        const float4* s1 = (const float4*)(z1 + (size_t)b0 * CR_LEN);
        float4* d1 = (float4*)&z1_s[0][0];
        const int n1 = nrow * (CR_LEN / 4);
        for (int idx = tid; idx < n1; idx += NTHREADS) d1[idx] = s1[idx];
        const float4* s2 = (const float4*)(xc + (size_t)b0 * (CR_LEN + PR_LEN) * 3);
        float4* d2 = (float4*)&xc_s[0][0];
        const int n2 = nrow * ((CR_LEN + PR_LEN) * 3 / 4);
        for (int idx = tid; idx < n2; idx += NTHREADS) d2[idx] = s2[idx];
    }
    if (tid < HID)                 wmu_s[tid] = W_mu[tid];
    else if (tid < 2 * HID)        wsg_s[tid - HID] = W_sig[tid - HID];
    else if (tid == 2 * HID)       bmu_s = b_mu[0];
    else if (tid == 2 * HID + 1)   bsg_s = b_sig[0];

    float4 w0[10], w1[10], w2[10], w3[10];
    {
        const float4* p0 = (const float4*)(W_hh + (0 * HID + j) * HID);
        const float4* p1 = (const float4*)(W_hh + (1 * HID + j) * HID);
        const float4* p2 = (const float4*)(W_hh + (2 * HID + j) * HID);
        const float4* p3 = (const float4*)(W_hh + (3 * HID + j) * HID);
#pragma unroll
        for (int q = 0; q < 10; q++) { w0[q] = p0[q]; w1[q] = p1[q]; w2[q] = p2[q]; w3[q] = p3[q]; }
    }

    float fA[4], fC[4], fx0[4], fx1[4], fx2[4];
#pragma unroll
    for (int g = 0; g < 4; g++) {
        const int row = g * HID + j;
        const float* wr = W_ih + row * 23;
        float a = 0.0f, cc = b_ih[row] + b_hh[row];
#pragma unroll
        for (int e = 0; e < 20; e++) {
            float wv = wr[e];
            a  = fmaf(wv, W_emb[e], a);
            cc = fmaf(wv, b_emb[e], cc);
        }
        fA[g] = a; fC[g] = cc;
        fx0[g] = wr[20]; fx1[g] = wr[21]; fx2[g] = wr[22];
    }

    __syncthreads();

    float v = 0.0f, inv_v = 0.0f;
    if (active) {
        float s = 0.0f;
#pragma unroll
        for (int q = 0; q < CR_LEN / 4; q++) {
            float4 zz = *(const float4*)&z1_s[r][4 * q];
            s += zz.x + zz.y + zz.z + zz.w;
        }
        v = s * (1.0f / (float)CR_LEN) + 1.0f;
        inv_v = 1.0f / v;
    }

    // eps: JAX threefry PARTITIONABLE path (verified R3): ctr=(0,i), bits=o0^o1
    if (active && j < PR_LEN) {
        unsigned i = (unsigned)j * B_TOTAL + (unsigned)b;
        unsigned o0, o1;
        threefry2x32(0u, 42u, 0u, i, o0, o1);
        unsigned bits = o0 ^ o1;
        float f = __uint_as_float((bits >> 9) | 0x3F800000u) - 1.0f;
        const float lo = -0.99999994f;
        float u = fmaxf(lo, fmaf(f, 2.0f, lo));
        eps_s[r][j] = 1.41421356237f * erfinv_f(u);
    }

    if (active) { h_s[0][r][j] = 0.0f; }
    float c_st = 0.0f, h_st = 0.0f;
    __syncthreads();

    int cur = 0;   // which h_s buffer holds h_t

    auto lstm_step = [&](float z1n, float xa, float xb, float xv) {
        float a0 = fmaf(fA[0], z1n, fC[0]);
        float a1 = fmaf(fA[1], z1n, fC[1]);
        float a2 = fmaf(fA[2], z1n, fC[2]);
        float a3 = fmaf(fA[3], z1n, fC[3]);
        a0 = fmaf(fx0[0], xa, a0); a1 = fmaf(fx0[1], xa, a1);
        a2 = fmaf(fx0[2], xa, a2); a3 = fmaf(fx0[3], xa, a3);
        a0 = fmaf(fx1[0], xb, a0); a1 = fmaf(fx1[1], xb, a1);
        a2 = fmaf(fx1[2], xb, a2); a3 = fmaf(fx1[3], xb, a3);
        a0 = fmaf(fx2[0], xv, a0); a1 = fmaf(fx2[1], xv, a1);
        a2 = fmaf(fx2[2], xv, a2); a3 = fmaf(fx2[3], xv, a3);
#pragma unroll
        for (int q = 0; q < 10; q++) {
            float4 h4 = *(const float4*)&h_s[cur][r][4 * q];
            a0 = fmaf(w0[q].x, h4.x, a0); a0 = fmaf(w0[q].y, h4.y, a0);
            a0 = fmaf(w0[q].z, h4.z, a0); a0 = fmaf(w0[q].w, h4.w, a0);
            a1 = fmaf(w1[q].x, h4.x, a1); a1 = fmaf(w1[q].y, h4.y, a1);
            a1 = fmaf(w1[q].z, h4.z, a1); a1 = fmaf(w1[q].w, h4.w, a1);
            a2 = fmaf(w2[q].x, h4.x, a2); a2 = fmaf(w2[q].y, h4.y, a2);
            a2 = fmaf(w2[q].z, h4.z, a2); a2 = fmaf(w2[q].w, h4.w, a2);
            a3 = fmaf(w3[q].x, h4.x, a3); a3 = fmaf(w3[q].y, h4.y, a3);
            a3 = fmaf(w3[q].z, h4.z, a3); a3 = fmaf(w3[q].w, h4.w, a3);
        }
        float gi = sigmoid_f(a0);
        float gf = sigmoid_f(a1);
        float gg = tanh_f(a2);
        float go = sigmoid_f(a3);
        c_st = fmaf(gf, c_st, gi * gg);
        h_st = go * tanh_f(c_st);
    };

    // conditioning: ONE barrier per step (write next-h into alternate buffer)
    for (int t = 0; t < CR_LEN - 1; t++) {
        if (active) {
            float z1n = z1_s[r][t] * inv_v;
            float xa = xc_s[r][3 * (t + 1) + 0];
            float xb = xc_s[r][3 * (t + 1) + 1];
            float xv = xc_s[r][3 * (t + 1) + 2];
            lstm_step(z1n, xa, xb, xv);
            h_s[cur ^ 1][r][j] = h_st;
        }
        __syncthreads();
        cur ^= 1;
    }

    if (active && j == 0) y_s[r] = z1_s[r][CR_LEN - 1];
    __syncthreads();

    // prediction: needs y feedback -> 2 barriers per step (24 steps only)
    for (int t = 0; t < PR_LEN; t++) {
        if (active) {
            float z1n = y_s[r] * inv_v;
            float xa = xc_s[r][3 * (CR_LEN + t) + 0];
            float xb = xc_s[r][3 * (CR_LEN + t) + 1];
            float xv = xc_s[r][3 * (CR_LEN + t) + 2];
            lstm_step(z1n, xa, xb, xv);
            h_s[cur ^ 1][r][j] = h_st;
        }
        __syncthreads();
        cur ^= 1;
        if (active && j == 0) {
            float mu = bmu_s, sp = bsg_s;
#pragma unroll
            for (int q = 0; q < 10; q++) {
                float4 h4 = *(const float4*)&h_s[cur][r][4 * q];
                float4 wm = *(const float4*)&wmu_s[4 * q];
                float4 ws = *(const float4*)&wsg_s[4 * q];
                mu = fmaf(wm.x, h4.x, mu); mu = fmaf(wm.y, h4.y, mu);
                mu = fmaf(wm.z, h4.z, mu); mu = fmaf(wm.w, h4.w, mu);
                sp = fmaf(ws.x, h4.x, sp); sp = fmaf(ws.y, h4.y, sp);
                sp = fmaf(ws.z, h4.z, sp); sp = fmaf(ws.w, h4.w, sp);
            }
            float sigma = fmaxf(sp, 0.0f) + log1pf(__expf(-fabsf(sp)));
            float y = fmaf(sigma, eps_s[r][t], mu);
            y_s[r] = y;
            const int ob = b * PR_LEN + t;
            float poison = (b == 0 && t == 0) ? kat_poison() : 0.0f;
            out[ob]                  = y * v + poison;
            out[OUT_STRIDE + ob]     = mu * v;
            out[2 * OUT_STRIDE + ob] = sigma * v;
        }
        __syncthreads();
    }
}

extern "C" void kernel_launch(void* const* d_in, const int* in_sizes, int n_in,
                              void* d_out, int out_size, void* d_ws, size_t ws_size,
                              hipStream_t stream) {
    const float* z1    = (const float*)d_in[0];
    const float* xc    = (const float*)d_in[1];
    const float* W_emb = (const float*)d_in[2];
    const float* b_emb = (const float*)d_in[3];
    const float* W_ih  = (const float*)d_in[4];
    const float* b_ih  = (const float*)d_in[5];
    const float* W_hh  = (const float*)d_in[6];
    const float* b_hh  = (const float*)d_in[7];
    const float* W_mu  = (const float*)d_in[8];
    const float* b_mu  = (const float*)d_in[9];
    const float* W_sig = (const float*)d_in[10];
    const float* b_sig = (const float*)d_in[11];
    float* out = (float*)d_out;

    dim3 grid((B_TOTAL + ROWS - 1) / ROWS);
    dim3 block(NTHREADS);
    deepar_kernel<<<grid, block, 0, stream>>>(z1, xc, W_emb, b_emb, W_ih, b_ih,
                                              W_hh, b_hh, W_mu, b_mu, W_sig, b_sig,
                                              out);
}